// Round 1
// baseline (182.854 us; speedup 1.0000x reference)
//
#include <hip/hip_runtime.h>
#include <math.h>

#define S 4096
#define CC 64
#define HH 8
#define DD 8
#define EPS 1e-5f

#if __has_builtin(__builtin_amdgcn_exp2f)
#define EXP2F(x) __builtin_amdgcn_exp2f(x)
#else
#define EXP2F(x) exp2f(x)
#endif

// ws layout (floats):
#define WS_PSUM 0            // [64] partial sums
#define WS_PSQ  64           // [64] partial sumsq
#define WS_MU   128          // [8]
#define WS_RS   136          // [8]
#define WS_EFFB 144          // [192] folded bias for qkv
#define WS_EFFW 512          // [192*64] folded weights for qkv
#define WS_QKV  16384        // [192*4096]
#define WS_ATT  (16384 + 192*4096)  // [64*4096]

// ---------------- GroupNorm stage 1: partial sums ----------------
// 64 blocks; block b reduces x[b*4096 .. b*4096+4096)
__global__ __launch_bounds__(256) void k_gnstat1(const float* __restrict__ x,
                                                 float* __restrict__ ws) {
    int b = blockIdx.x;
    int tid = threadIdx.x;
    const float4* p = (const float4*)(x + b * 4096);
    float s = 0.f, sq = 0.f;
    #pragma unroll
    for (int i = 0; i < 4; ++i) {
        float4 v = p[tid + i * 256];
        s  += v.x + v.y + v.z + v.w;
        sq += v.x * v.x + v.y * v.y + v.z * v.z + v.w * v.w;
    }
    #pragma unroll
    for (int m = 32; m >= 1; m >>= 1) {
        s  += __shfl_xor(s, m);
        sq += __shfl_xor(sq, m);
    }
    __shared__ float ls[4], lq[4];
    int w = tid >> 6;
    if ((tid & 63) == 0) { ls[w] = s; lq[w] = sq; }
    __syncthreads();
    if (tid == 0) {
        ws[WS_PSUM + b] = ls[0] + ls[1] + ls[2] + ls[3];
        ws[WS_PSQ  + b] = lq[0] + lq[1] + lq[2] + lq[3];
    }
}

// ---------------- GroupNorm stage 2: finalize mu / rsigma ----------------
// 1 block, 64 threads; 8 partials per group are consecutive
__global__ void k_gnstat2(float* __restrict__ ws) {
    int t = threadIdx.x;
    float s  = ws[WS_PSUM + t];
    float sq = ws[WS_PSQ + t];
    #pragma unroll
    for (int m = 1; m < 8; m <<= 1) {
        s  += __shfl_xor(s, m);
        sq += __shfl_xor(sq, m);
    }
    if ((t & 7) == 0) {
        int g = t >> 3;
        const float inv_n = 1.0f / 32768.0f;
        float mu  = s * inv_n;
        float var = sq * inv_n - mu * mu;
        ws[WS_MU + g] = mu;
        ws[WS_RS + g] = rsqrtf(var + EPS);
    }
}

// ---------------- Fold GN affine into qkv weights ----------------
// 192 blocks x 64 threads: effW[o][c] = qkv_w[o][c]*rs[g]*gnw[c];
// effB[o] = sum_c qkv_w[o][c]*(gnb[c] - mu[g]*rs[g]*gnw[c])
__global__ void k_fold(const float* __restrict__ qkvw,
                       const float* __restrict__ gnw,
                       const float* __restrict__ gnb,
                       float* __restrict__ ws) {
    int o = blockIdx.x;
    int c = threadIdx.x;
    int g = c >> 3;
    float mu = ws[WS_MU + g], rs = ws[WS_RS + g];
    float w  = qkvw[o * 64 + c];
    float a  = rs * gnw[c];
    float bb = gnb[c] - mu * a;
    ws[WS_EFFW + o * 64 + c] = w * a;
    float pb = w * bb;
    #pragma unroll
    for (int m = 1; m < 64; m <<= 1) pb += __shfl_xor(pb, m);
    if (c == 0) ws[WS_EFFB + o] = pb;
}

// ---------------- QKV projection: qkv[o][s] = effW[o][:] . x[:][s] + effB[o] ----------------
// grid (4, 24), block 256: s-tile 1024 (thread: 4 consecutive s), o-tile 8
__global__ __launch_bounds__(256) void k_qkv(const float* __restrict__ x,
                                             float* __restrict__ ws) {
    int tid = threadIdx.x;
    int sbase = blockIdx.x * 1024 + tid * 4;
    int o0 = blockIdx.y * 8;
    float acc[8][4];
    #pragma unroll
    for (int o = 0; o < 8; ++o) {
        float b = ws[WS_EFFB + o0 + o];
        acc[o][0] = b; acc[o][1] = b; acc[o][2] = b; acc[o][3] = b;
    }
    for (int c = 0; c < 64; ++c) {
        float4 xv = *(const float4*)(x + c * S + sbase);
        #pragma unroll
        for (int o = 0; o < 8; ++o) {
            float w = ws[WS_EFFW + (o0 + o) * 64 + c];
            acc[o][0] = fmaf(w, xv.x, acc[o][0]);
            acc[o][1] = fmaf(w, xv.y, acc[o][1]);
            acc[o][2] = fmaf(w, xv.z, acc[o][2]);
            acc[o][3] = fmaf(w, xv.w, acc[o][3]);
        }
    }
    #pragma unroll
    for (int o = 0; o < 8; ++o) {
        float4 r = make_float4(acc[o][0], acc[o][1], acc[o][2], acc[o][3]);
        *(float4*)(ws + WS_QKV + (o0 + o) * S + sbase) = r;
    }
}

// ---------------- Attention (flash-style, no-max softmax) ----------------
// grid (64 q-tiles, 8 heads), block 256.
// 16 query-groups x 16 key-slices; each thread: 4 queries, keys t = ks + 16*j.
__global__ __launch_bounds__(256) void k_attn(float* __restrict__ ws) {
    const int h = blockIdx.y;
    const int s0 = blockIdx.x * 64;
    const int tid = threadIdx.x;

    const float* qg = ws + WS_QKV + (h * DD) * S;
    const float* kg = ws + WS_QKV + (64 + h * DD) * S;
    const float* vg = ws + WS_QKV + (128 + h * DD) * S;

    __shared__ float qs[DD][64];
    __shared__ float kt[DD][64];
    __shared__ float vt[DD][64];
    __shared__ float outs[DD][64];

    // load+scale q tile (512 floats, threads 0..127)
    if (tid < 128) {
        int d = tid >> 4, i4 = tid & 15;
        const float sc = 0.35355339059327373f * 1.44269504088896340f; // 8^-0.5 * log2(e)
        float4 qv = *(const float4*)(qg + d * S + s0 + i4 * 4);
        qs[d][i4 * 4 + 0] = qv.x * sc;
        qs[d][i4 * 4 + 1] = qv.y * sc;
        qs[d][i4 * 4 + 2] = qv.z * sc;
        qs[d][i4 * 4 + 3] = qv.w * sc;
    }
    __syncthreads();

    const int qgid = tid >> 4;   // 0..15
    const int ks = tid & 15;     // 0..15

    float qr[4][8];
    #pragma unroll
    for (int qq = 0; qq < 4; ++qq)
        #pragma unroll
        for (int d = 0; d < 8; ++d)
            qr[qq][d] = qs[d][qgid * 4 + qq];

    float acc[4][8];
    float l[4] = {0.f, 0.f, 0.f, 0.f};
    #pragma unroll
    for (int qq = 0; qq < 4; ++qq)
        #pragma unroll
        for (int d = 0; d < 8; ++d) acc[qq][d] = 0.f;

    // k/v staging pointers for this thread (one float4 of the 4KB tile each)
    const int ld_d = tid >> 4;            // 0..15 : <8 -> k, else v
    const int ld_t4 = tid & 15;
    const float* ld_src = (ld_d < 8) ? (kg + ld_d * S + ld_t4 * 4)
                                     : (vg + (ld_d - 8) * S + ld_t4 * 4);
    float* ld_dst = (ld_d < 8) ? &kt[ld_d][ld_t4 * 4] : &vt[ld_d - 8][ld_t4 * 4];

    for (int t0 = 0; t0 < S; t0 += 64) {
        float4 val = *(const float4*)(ld_src + t0);  // global load before barrier
        __syncthreads();                              // previous tile fully consumed
        *(float4*)ld_dst = val;
        __syncthreads();

        #pragma unroll
        for (int j = 0; j < 4; ++j) {
            int t = ks + 16 * j;
            float kv[8], vv[8];
            #pragma unroll
            for (int d = 0; d < 8; ++d) kv[d] = kt[d][t];
            #pragma unroll
            for (int d = 0; d < 8; ++d) vv[d] = vt[d][t];
            #pragma unroll
            for (int qq = 0; qq < 4; ++qq) {
                float sc = qr[qq][0] * kv[0];
                #pragma unroll
                for (int d = 1; d < 8; ++d) sc = fmaf(qr[qq][d], kv[d], sc);
                float p = EXP2F(sc);
                l[qq] += p;
                #pragma unroll
                for (int d = 0; d < 8; ++d) acc[qq][d] = fmaf(p, vv[d], acc[qq][d]);
            }
        }
    }

    // reduce across the 16 key-slices (consecutive lanes)
    #pragma unroll
    for (int m = 8; m >= 1; m >>= 1) {
        #pragma unroll
        for (int qq = 0; qq < 4; ++qq) {
            l[qq] += __shfl_xor(l[qq], m);
            #pragma unroll
            for (int d = 0; d < 8; ++d) acc[qq][d] += __shfl_xor(acc[qq][d], m);
        }
    }
    if (ks == 0) {
        #pragma unroll
        for (int qq = 0; qq < 4; ++qq) {
            float inv = 1.0f / l[qq];
            #pragma unroll
            for (int d = 0; d < 8; ++d) outs[d][qgid * 4 + qq] = acc[qq][d] * inv;
        }
    }
    __syncthreads();

    float* att = ws + WS_ATT + (h * DD) * S + s0;
    #pragma unroll
    for (int e = tid; e < DD * 64; e += 256) {
        int d = e >> 6, i = e & 63;
        att[d * S + i] = outs[d][i];
    }
}

// ---------------- Out projection + bias + residual ----------------
// grid (4, 8), block 256: s-tile 1024, o-tile 8
__global__ __launch_bounds__(256) void k_out(const float* __restrict__ x,
                                             const float* __restrict__ outw,
                                             const float* __restrict__ outb,
                                             const float* __restrict__ ws,
                                             float* __restrict__ out) {
    int tid = threadIdx.x;
    int sbase = blockIdx.x * 1024 + tid * 4;
    int o0 = blockIdx.y * 8;
    float acc[8][4];
    #pragma unroll
    for (int o = 0; o < 8; ++o) {
        float b = outb[o0 + o];
        acc[o][0] = b; acc[o][1] = b; acc[o][2] = b; acc[o][3] = b;
    }
    for (int c = 0; c < 64; ++c) {
        float4 av = *(const float4*)(ws + WS_ATT + c * S + sbase);
        #pragma unroll
        for (int o = 0; o < 8; ++o) {
            float w = outw[(o0 + o) * 64 + c];
            acc[o][0] = fmaf(w, av.x, acc[o][0]);
            acc[o][1] = fmaf(w, av.y, acc[o][1]);
            acc[o][2] = fmaf(w, av.z, acc[o][2]);
            acc[o][3] = fmaf(w, av.w, acc[o][3]);
        }
    }
    #pragma unroll
    for (int o = 0; o < 8; ++o) {
        float4 xv = *(const float4*)(x + (o0 + o) * S + sbase);
        float4 r = make_float4(acc[o][0] + xv.x, acc[o][1] + xv.y,
                               acc[o][2] + xv.z, acc[o][3] + xv.w);
        *(float4*)(out + (o0 + o) * S + sbase) = r;
    }
}

extern "C" void kernel_launch(void* const* d_in, const int* in_sizes, int n_in,
                              void* d_out, int out_size, void* d_ws, size_t ws_size,
                              hipStream_t stream) {
    const float* x    = (const float*)d_in[0];
    const float* gnw  = (const float*)d_in[1];
    const float* gnb  = (const float*)d_in[2];
    const float* qkvw = (const float*)d_in[3];
    const float* outw = (const float*)d_in[4];
    const float* outb = (const float*)d_in[5];
    float* out = (float*)d_out;
    float* ws  = (float*)d_ws;

    hipLaunchKernelGGL(k_gnstat1, dim3(64), dim3(256), 0, stream, x, ws);
    hipLaunchKernelGGL(k_gnstat2, dim3(1), dim3(64), 0, stream, ws);
    hipLaunchKernelGGL(k_fold, dim3(192), dim3(64), 0, stream, qkvw, gnw, gnb, ws);
    hipLaunchKernelGGL(k_qkv, dim3(4, 24), dim3(256), 0, stream, x, ws);
    hipLaunchKernelGGL(k_attn, dim3(64, 8), dim3(256), 0, stream, ws);
    hipLaunchKernelGGL(k_out, dim3(4, 8), dim3(256), 0, stream, x, outw, outb, ws, out);
}

// Round 3
// 124.335 us; speedup vs baseline: 1.4707x; 1.4707x over previous
//
#include <hip/hip_runtime.h>
#include <math.h>

#define S 4096
#define EPS 1e-5f

// ws float-index offsets
#define WS_PSUM 0            // [64]
#define WS_PSQ  64           // [64]
#define WS_EFFB 144          // [192]
#define WS_EFFW 512          // [192*64]
#define WS_ATT  16384        // [64*4096] f32
// ws byte offsets for f16 regions (each 512 KB)
#define QT_B 1310720
#define KT_B 1835008
#define VB_B 2359296

typedef _Float16 h8_t __attribute__((ext_vector_type(8)));
typedef __fp16   fp16v2 __attribute__((ext_vector_type(2)));
typedef float    f4_t __attribute__((ext_vector_type(4)));

union H8 { h8_t h; int4 v; int i[4]; };

static __device__ __forceinline__ int pkrtz(float a, float b) {
    fp16v2 p = __builtin_amdgcn_cvt_pkrtz(a, b);
    union { fp16v2 h; int i; } u; u.h = p; return u.i;
}

// ---------------- GroupNorm stage 1: per-channel partial sums ----------------
__global__ __launch_bounds__(256) void k_gnstat1(const float* __restrict__ x,
                                                 float* __restrict__ ws) {
    int b = blockIdx.x;
    int tid = threadIdx.x;
    const float4* p = (const float4*)(x + b * 4096);
    float s = 0.f, sq = 0.f;
    #pragma unroll
    for (int i = 0; i < 4; ++i) {
        float4 v = p[tid + i * 256];
        s  += v.x + v.y + v.z + v.w;
        sq += v.x * v.x + v.y * v.y + v.z * v.z + v.w * v.w;
    }
    #pragma unroll
    for (int m = 32; m >= 1; m >>= 1) {
        s  += __shfl_xor(s, m);
        sq += __shfl_xor(sq, m);
    }
    __shared__ float ls[4], lq[4];
    int w = tid >> 6;
    if ((tid & 63) == 0) { ls[w] = s; lq[w] = sq; }
    __syncthreads();
    if (tid == 0) {
        ws[WS_PSUM + b] = ls[0] + ls[1] + ls[2] + ls[3];
        ws[WS_PSQ  + b] = lq[0] + lq[1] + lq[2] + lq[3];
    }
}

// ---------------- Fold GN affine into qkv weights (stats finalized inline) ----------------
__global__ void k_fold(const float* __restrict__ qkvw,
                       const float* __restrict__ gnw,
                       const float* __restrict__ gnb,
                       float* __restrict__ ws) {
    int o = blockIdx.x;
    int c = threadIdx.x;
    float s  = ws[WS_PSUM + c];
    float sq = ws[WS_PSQ + c];
    #pragma unroll
    for (int m = 1; m < 8; m <<= 1) {   // reduce within the 8 channels of c's group
        s  += __shfl_xor(s, m);
        sq += __shfl_xor(sq, m);
    }
    const float inv_n = 1.0f / 32768.0f;
    float mu  = s * inv_n;
    float var = sq * inv_n - mu * mu;
    float rs  = rsqrtf(var + EPS);
    float w  = qkvw[o * 64 + c];
    float a  = rs * gnw[c];
    float bb = gnb[c] - mu * a;
    ws[WS_EFFW + o * 64 + c] = w * a;
    float pb = w * bb;
    #pragma unroll
    for (int m = 1; m < 64; m <<= 1) pb += __shfl_xor(pb, m);
    if (c == 0) ws[WS_EFFB + o] = pb;
}

// ---------------- QKV projection, writes f16 MFMA-layout buffers ----------------
// grid (8, 24), block 256: s-tile 512 (thread: 2 s), o-tile 8 (one head-slice)
__global__ __launch_bounds__(256) void k_qkv(const float* __restrict__ x,
                                             float* __restrict__ ws) {
    __shared__ float lw[512];
    __shared__ float lb[8];
    int tid = threadIdx.x;
    int o0 = blockIdx.y * 8;
    int sbase = blockIdx.x * 512 + tid * 2;
    lw[tid]       = ws[WS_EFFW + o0 * 64 + tid];
    lw[tid + 256] = ws[WS_EFFW + o0 * 64 + 256 + tid];
    if (tid < 8) lb[tid] = ws[WS_EFFB + o0 + tid];
    __syncthreads();

    float a0[8], a1[8];
    #pragma unroll
    for (int o = 0; o < 8; ++o) { a0[o] = lb[o]; a1[o] = lb[o]; }
    for (int c = 0; c < 64; ++c) {
        float2 xv = *(const float2*)(x + c * S + sbase);
        #pragma unroll
        for (int o = 0; o < 8; ++o) {
            float w = lw[o * 64 + c];
            a0[o] = fmaf(w, xv.x, a0[o]);
            a1[o] = fmaf(w, xv.y, a1[o]);
        }
    }

    char* base = (char*)ws;
    if (o0 < 64) {                       // Q -> Qt[h][s][d], pre-scaled by 8^-0.5*log2(e)
        const float qsc = 0.51006776f;
        int hh = o0 >> 3;
        #pragma unroll
        for (int j = 0; j < 2; ++j) {
            const float* a = j ? a1 : a0;
            int4 r;
            r.x = pkrtz(a[0] * qsc, a[1] * qsc);
            r.y = pkrtz(a[2] * qsc, a[3] * qsc);
            r.z = pkrtz(a[4] * qsc, a[5] * qsc);
            r.w = pkrtz(a[6] * qsc, a[7] * qsc);
            *(int4*)(base + QT_B + (size_t)(hh * 4096 + sbase + j) * 16) = r;
        }
    } else if (o0 < 128) {               // K -> Kt[h][t][d]
        int hh = (o0 - 64) >> 3;
        #pragma unroll
        for (int j = 0; j < 2; ++j) {
            const float* a = j ? a1 : a0;
            int4 r;
            r.x = pkrtz(a[0], a[1]);
            r.y = pkrtz(a[2], a[3]);
            r.z = pkrtz(a[4], a[5]);
            r.w = pkrtz(a[6], a[7]);
            *(int4*)(base + KT_B + (size_t)(hh * 4096 + sbase + j) * 16) = r;
        }
    } else {                             // V -> Vb[h][d][t]
        int hh = (o0 - 128) >> 3;
        #pragma unroll
        for (int d = 0; d < 8; ++d) {
            int r = pkrtz(a0[d], a1[d]);
            *(int*)(base + VB_B + (size_t)((hh * 8 + d) * 4096 + sbase) * 2) = r;
        }
    }
}

// ---------------- Attention via f16 MFMA ----------------
// grid (128, 8): block = 32 queries (2 MFMA subtiles), 4 waves = 4 t-quarters.
// St[t][s] = K^T x Q (K=8 padded to 32); exp2; P^T via padded LDS tile into
// B-layout; O^T[d][s] += (V|ones) x P^T  -> row 8 of acc is the softmax denom.
__global__ __launch_bounds__(256) void k_attn(float* __restrict__ ws) {
    const int h = blockIdx.y;
    const int q0 = blockIdx.x * 32;
    const int tid = threadIdx.x;
    const int w = tid >> 6;          // t-quarter
    const int lane = tid & 63;
    const int col = lane & 15;
    const int quad = lane >> 4;

    const char* base = (const char*)ws;
    const _Float16* Qt = (const _Float16*)(base + QT_B) + (size_t)h * 4096 * 8;
    const _Float16* Kt = (const _Float16*)(base + KT_B) + (size_t)h * 4096 * 8;
    const _Float16* Vb = (const _Float16*)(base + VB_B) + (size_t)h * 8 * 4096;

    __shared__ _Float16 Plds[4][2][16][40];   // +8 half pad -> 2-way banks (free)
    __shared__ f4_t red[3][2][64];

    H8 qf0, qf1;
    qf0.i[0] = qf0.i[1] = qf0.i[2] = qf0.i[3] = 0;
    qf1 = qf0;
    if (quad == 0) {
        qf0.v = *(const int4*)(Qt + (size_t)(q0 + col) * 8);
        qf1.v = *(const int4*)(Qt + (size_t)(q0 + 16 + col) * 8);
    }

    const int tbase = w * 1024;
    f4_t acc0 = {0.f, 0.f, 0.f, 0.f};
    f4_t acc1 = {0.f, 0.f, 0.f, 0.f};

    auto loadKV = [&](H8& K0, H8& K1, H8& V, int tt) {
        K0.i[0] = K0.i[1] = K0.i[2] = K0.i[3] = 0;
        K1 = K0;
        if (quad == 0) {
            K0.v = *(const int4*)(Kt + (size_t)(tt + col) * 8);
            K1.v = *(const int4*)(Kt + (size_t)(tt + 16 + col) * 8);
        }
        if (col < 8) {
            V.v = *(const int4*)(Vb + (size_t)col * 4096 + tt + quad * 8);
        } else if (col == 8) {
            V.i[0] = V.i[1] = V.i[2] = V.i[3] = 0x3C003C00;  // f16 1.0 pairs
        } else {
            V.i[0] = V.i[1] = V.i[2] = V.i[3] = 0;
        }
    };

    H8 kf0, kf1, vf;
    loadKV(kf0, kf1, vf, tbase);

    _Float16* Prow0 = &Plds[w][0][0][0];
    _Float16* Prow1 = &Plds[w][1][0][0];
    const f4_t z = {0.f, 0.f, 0.f, 0.f};

    for (int it = 0; it < 32; ++it) {
        H8 nk0 = kf0, nk1 = kf1, nv = vf;
        if (it < 31) loadKV(nk0, nk1, nv, tbase + (it + 1) * 32);

        f4_t s00 = __builtin_amdgcn_mfma_f32_16x16x32_f16(kf0.h, qf0.h, z, 0, 0, 0);
        f4_t s01 = __builtin_amdgcn_mfma_f32_16x16x32_f16(kf1.h, qf0.h, z, 0, 0, 0);
        f4_t s10 = __builtin_amdgcn_mfma_f32_16x16x32_f16(kf0.h, qf1.h, z, 0, 0, 0);
        f4_t s11 = __builtin_amdgcn_mfma_f32_16x16x32_f16(kf1.h, qf1.h, z, 0, 0, 0);

        #pragma unroll
        for (int r = 0; r < 4; ++r) {
            s00[r] = exp2f(s00[r]); s01[r] = exp2f(s01[r]);
            s10[r] = exp2f(s10[r]); s11[r] = exp2f(s11[r]);
        }

        // C-layout (rows t=4*quad+r / 16+4*quad+r at col s) -> LDS P[s][t]
        int2 w0a = { pkrtz(s00[0], s00[1]), pkrtz(s00[2], s00[3]) };
        int2 w0b = { pkrtz(s01[0], s01[1]), pkrtz(s01[2], s01[3]) };
        *(int2*)(Prow0 + col * 40 + quad * 4)      = w0a;
        *(int2*)(Prow0 + col * 40 + 16 + quad * 4) = w0b;
        int2 w1a = { pkrtz(s10[0], s10[1]), pkrtz(s10[2], s10[3]) };
        int2 w1b = { pkrtz(s11[0], s11[1]), pkrtz(s11[2], s11[3]) };
        *(int2*)(Prow1 + col * 40 + quad * 4)      = w1a;
        *(int2*)(Prow1 + col * 40 + 16 + quad * 4) = w1b;

        // B-layout read: lane(quad,col) takes P[s=col][t=quad*8..quad*8+7]
        H8 p0, p1;
        p0.v = *(const int4*)(Prow0 + col * 40 + quad * 8);
        p1.v = *(const int4*)(Prow1 + col * 40 + quad * 8);

        acc0 = __builtin_amdgcn_mfma_f32_16x16x32_f16(vf.h, p0.h, acc0, 0, 0, 0);
        acc1 = __builtin_amdgcn_mfma_f32_16x16x32_f16(vf.h, p1.h, acc1, 0, 0, 0);

        kf0 = nk0; kf1 = nk1; vf = nv;
    }

    if (w > 0) { red[w - 1][0][lane] = acc0; red[w - 1][1][lane] = acc1; }
    __syncthreads();
    if (w == 0) {
        #pragma unroll
        for (int r = 0; r < 3; ++r) {
            f4_t t0 = red[r][0][lane];
            f4_t t1 = red[r][1][lane];
            acc0 += t0; acc1 += t1;
        }
        float inv0 = 1.0f / __shfl(acc0[0], 32 + col, 64);  // row 8 = denom
        float inv1 = 1.0f / __shfl(acc1[0], 32 + col, 64);
        if (quad < 2) {
            float* att = ws + WS_ATT + (size_t)(h * 8 + quad * 4) * S + q0;
            #pragma unroll
            for (int r = 0; r < 4; ++r) {
                att[r * S + col]      = acc0[r] * inv0;
                att[r * S + 16 + col] = acc1[r] * inv1;
            }
        }
    }
}

// ---------------- Out projection + bias + residual ----------------
// grid (16, 8), block 256: s-tile 256 (thread: 1 s), o-tile 8
__global__ __launch_bounds__(256) void k_out(const float* __restrict__ x,
                                             const float* __restrict__ outw,
                                             const float* __restrict__ outb,
                                             const float* __restrict__ ws,
                                             float* __restrict__ out) {
    __shared__ float lw[512];
    __shared__ float lb[8];
    int tid = threadIdx.x;
    int o0 = blockIdx.y * 8;
    int s = blockIdx.x * 256 + tid;
    lw[tid]       = outw[o0 * 64 + tid];
    lw[tid + 256] = outw[o0 * 64 + 256 + tid];
    if (tid < 8) lb[tid] = outb[o0 + tid];
    __syncthreads();

    float acc[8];
    #pragma unroll
    for (int o = 0; o < 8; ++o) acc[o] = lb[o];
    const float* att = ws + WS_ATT;
    for (int c = 0; c < 64; ++c) {
        float av = att[c * S + s];
        #pragma unroll
        for (int o = 0; o < 8; ++o) acc[o] = fmaf(lw[o * 64 + c], av, acc[o]);
    }
    #pragma unroll
    for (int o = 0; o < 8; ++o)
        out[(o0 + o) * S + s] = acc[o] + x[(o0 + o) * S + s];
}

extern "C" void kernel_launch(void* const* d_in, const int* in_sizes, int n_in,
                              void* d_out, int out_size, void* d_ws, size_t ws_size,
                              hipStream_t stream) {
    const float* x    = (const float*)d_in[0];
    const float* gnw  = (const float*)d_in[1];
    const float* gnb  = (const float*)d_in[2];
    const float* qkvw = (const float*)d_in[3];
    const float* outw = (const float*)d_in[4];
    const float* outb = (const float*)d_in[5];
    float* out = (float*)d_out;
    float* ws  = (float*)d_ws;

    hipLaunchKernelGGL(k_gnstat1, dim3(64), dim3(256), 0, stream, x, ws);
    hipLaunchKernelGGL(k_fold, dim3(192), dim3(64), 0, stream, qkvw, gnw, gnb, ws);
    hipLaunchKernelGGL(k_qkv, dim3(8, 24), dim3(256), 0, stream, x, ws);
    hipLaunchKernelGGL(k_attn, dim3(128, 8), dim3(256), 0, stream, ws);
    hipLaunchKernelGGL(k_out, dim3(16, 8), dim3(256), 0, stream, x, outw, outb, ws, out);
}

// Round 4
// 102.331 us; speedup vs baseline: 1.7869x; 1.2150x over previous
//
#include <hip/hip_runtime.h>
#include <math.h>

#define S 4096
#define EPS 1e-5f

#if __has_builtin(__builtin_amdgcn_exp2f)
#define EXP2F(x) __builtin_amdgcn_exp2f(x)
#else
#define EXP2F(x) exp2f(x)
#endif

// ws float-index offsets
#define WS_PSUM 0            // [64]
#define WS_PSQ  64           // [64]
#define WS_ATT  16384        // [64*4096] f32
// ws byte offsets for f16 regions (each 512 KB)
#define QT_B 1310720
#define KT_B 1835008
#define VB_B 2359296

typedef _Float16 h8_t __attribute__((ext_vector_type(8)));
typedef _Float16 h4_t __attribute__((ext_vector_type(4)));
typedef __fp16   fp16v2 __attribute__((ext_vector_type(2)));
typedef float    f4_t __attribute__((ext_vector_type(4)));

union H8 { h8_t h; int4 v; int i[4]; };
union H4 { h4_t h; int2 v; int i[2]; };

static __device__ __forceinline__ int pkrtz(float a, float b) {
    fp16v2 p = __builtin_amdgcn_cvt_pkrtz(a, b);
    union { fp16v2 h; int i; } u; u.h = p; return u.i;
}

// ---------------- GroupNorm stage 1: per-channel partial sums ----------------
__global__ __launch_bounds__(256) void k_gnstat1(const float* __restrict__ x,
                                                 float* __restrict__ ws) {
    int b = blockIdx.x;
    int tid = threadIdx.x;
    const float4* p = (const float4*)(x + b * 4096);
    float s = 0.f, sq = 0.f;
    #pragma unroll
    for (int i = 0; i < 4; ++i) {
        float4 v = p[tid + i * 256];
        s  += v.x + v.y + v.z + v.w;
        sq += v.x * v.x + v.y * v.y + v.z * v.z + v.w * v.w;
    }
    #pragma unroll
    for (int m = 32; m >= 1; m >>= 1) {
        s  += __shfl_xor(s, m);
        sq += __shfl_xor(sq, m);
    }
    __shared__ float ls[4], lq[4];
    int w = tid >> 6;
    if ((tid & 63) == 0) { ls[w] = s; lq[w] = sq; }
    __syncthreads();
    if (tid == 0) {
        ws[WS_PSUM + b] = ls[0] + ls[1] + ls[2] + ls[3];
        ws[WS_PSQ  + b] = lq[0] + lq[1] + lq[2] + lq[3];
    }
}

// ---------------- QKV projection (GN fold fused), writes f16 MFMA layouts ----------------
// grid (16, 24), block 256: s-tile 256 (1 s/thread), o-tile 8 (one head-slice)
__global__ __launch_bounds__(256) void k_qkv(const float* __restrict__ x,
                                             const float* __restrict__ qkvw,
                                             const float* __restrict__ gnw,
                                             const float* __restrict__ gnb,
                                             float* __restrict__ ws) {
    __shared__ float la[64], lb2[64], lw[512], lbias[8];
    int tid = threadIdx.x;
    int o0 = blockIdx.y * 8;
    int s = blockIdx.x * 256 + tid;

    if (tid < 64) {                 // finalize GN stats (redundant per block, cheap)
        float sm = ws[WS_PSUM + tid];
        float sq = ws[WS_PSQ + tid];
        #pragma unroll
        for (int m = 1; m < 8; m <<= 1) {
            sm += __shfl_xor(sm, m);
            sq += __shfl_xor(sq, m);
        }
        const float inv_n = 1.0f / 32768.0f;
        float mu  = sm * inv_n;
        float var = sq * inv_n - mu * mu;
        float rs  = rsqrtf(var + EPS);
        float a   = rs * gnw[tid];
        la[tid]  = a;
        lb2[tid] = gnb[tid] - mu * a;
    }
    __syncthreads();
    lw[tid]       = qkvw[o0 * 64 + tid]       * la[tid & 63];
    lw[tid + 256] = qkvw[o0 * 64 + 256 + tid] * la[tid & 63];
    {
        int wv = tid >> 6, ln = tid & 63;
        #pragma unroll
        for (int j = 0; j < 2; ++j) {
            int o = wv * 2 + j;
            float pb = qkvw[(o0 + o) * 64 + ln] * lb2[ln];
            #pragma unroll
            for (int m = 1; m < 64; m <<= 1) pb += __shfl_xor(pb, m);
            if (ln == 0) lbias[o] = pb;
        }
    }
    __syncthreads();

    float acc[8];
    #pragma unroll
    for (int o = 0; o < 8; ++o) acc[o] = lbias[o];
    for (int c = 0; c < 64; ++c) {
        float xv = x[c * S + s];
        #pragma unroll
        for (int o = 0; o < 8; ++o) acc[o] = fmaf(lw[o * 64 + c], xv, acc[o]);
    }

    char* base = (char*)ws;
    if (o0 < 64) {                       // Q -> Qt[h][s][d], pre-scaled by 8^-0.5*log2(e)
        const float qsc = 0.51006776f;
        int hh = o0 >> 3;
        int4 r;
        r.x = pkrtz(acc[0] * qsc, acc[1] * qsc);
        r.y = pkrtz(acc[2] * qsc, acc[3] * qsc);
        r.z = pkrtz(acc[4] * qsc, acc[5] * qsc);
        r.w = pkrtz(acc[6] * qsc, acc[7] * qsc);
        *(int4*)(base + QT_B + (size_t)(hh * 4096 + s) * 16) = r;
    } else if (o0 < 128) {               // K -> Kt[h][t][d]
        int hh = (o0 - 64) >> 3;
        int4 r;
        r.x = pkrtz(acc[0], acc[1]);
        r.y = pkrtz(acc[2], acc[3]);
        r.z = pkrtz(acc[4], acc[5]);
        r.w = pkrtz(acc[6], acc[7]);
        *(int4*)(base + KT_B + (size_t)(hh * 4096 + s) * 16) = r;
    } else {                             // V -> Vb[h][d][t]
        int hh = (o0 - 128) >> 3;
        _Float16* vb = (_Float16*)(base + VB_B);
        #pragma unroll
        for (int d = 0; d < 8; ++d)
            vb[(size_t)((hh * 8 + d) * 4096) + s] = (_Float16)acc[d];
    }
}

// ---------------- Attention via f16 MFMA ----------------
// grid (128, 8), block 512: 32 queries/block, 8 waves = 8 t-chunks of 512.
// QK uses 16x16x16 (K=16, frag=int2, half-empty instead of 3/4);
// PV uses 16x16x32 with (V|ones) so acc row 8 = softmax denominator.
__global__ __launch_bounds__(512, 8) void k_attn(float* __restrict__ ws) {
    const int h = blockIdx.y;
    const int q0 = blockIdx.x * 32;
    const int tid = threadIdx.x;
    const int w = tid >> 6;          // 0..7 t-chunk
    const int lane = tid & 63;
    const int col = lane & 15;
    const int quad = lane >> 4;

    const char* base = (const char*)ws;
    const _Float16* Qt = (const _Float16*)(base + QT_B) + (size_t)h * 4096 * 8;
    const _Float16* Kt = (const _Float16*)(base + KT_B) + (size_t)h * 4096 * 8;
    const _Float16* Vb = (const _Float16*)(base + VB_B) + (size_t)h * 8 * 4096;

    __shared__ _Float16 Plds[8][2][16][40];   // +8 half pad -> 2-way banks (free)
    __shared__ f4_t red[7][2][64];

    // Q frags (B-operand of 16x16x16): quads 0,1 hold d=quad*4..+3, rest zero
    H4 qf0, qf1;
    qf0.i[0] = qf0.i[1] = 0;
    qf1 = qf0;
    if (quad < 2) {
        qf0.v = *(const int2*)(Qt + (size_t)(q0 + col) * 8 + quad * 4);
        qf1.v = *(const int2*)(Qt + (size_t)(q0 + 16 + col) * 8 + quad * 4);
    }

    // K frags: zero-init once; masked loads in the loop touch only quads 0,1
    H4 kf0, kf1;
    kf0.i[0] = kf0.i[1] = 0;
    kf1 = kf0;
    // V frag (A-operand of 16x16x32): col<8 = data (loaded in loop),
    // col==8 = ones row (denominator), col>8 = zero — constants set once.
    H8 vf;
    {
        int c8 = (col == 8) ? 0x3C003C00 : 0;
        vf.i[0] = c8; vf.i[1] = c8; vf.i[2] = c8; vf.i[3] = c8;
    }

    f4_t acc0 = {0.f, 0.f, 0.f, 0.f};
    f4_t acc1 = {0.f, 0.f, 0.f, 0.f};
    const f4_t z = {0.f, 0.f, 0.f, 0.f};
    _Float16* Prow0 = &Plds[w][0][0][0];
    _Float16* Prow1 = &Plds[w][1][0][0];

    const int tbase = w * 512;
    for (int it = 0; it < 16; ++it) {
        const int tt = tbase + it * 32;
        if (quad < 2) {
            kf0.v = *(const int2*)(Kt + (size_t)(tt + col) * 8 + quad * 4);
            kf1.v = *(const int2*)(Kt + (size_t)(tt + 16 + col) * 8 + quad * 4);
        }
        if (col < 8)
            vf.v = *(const int4*)(Vb + (size_t)col * 4096 + tt + quad * 8);

        f4_t s00 = __builtin_amdgcn_mfma_f32_16x16x16f16(kf0.h, qf0.h, z, 0, 0, 0);
        f4_t s01 = __builtin_amdgcn_mfma_f32_16x16x16f16(kf1.h, qf0.h, z, 0, 0, 0);
        f4_t s10 = __builtin_amdgcn_mfma_f32_16x16x16f16(kf0.h, qf1.h, z, 0, 0, 0);
        f4_t s11 = __builtin_amdgcn_mfma_f32_16x16x16f16(kf1.h, qf1.h, z, 0, 0, 0);

        #pragma unroll
        for (int r = 0; r < 4; ++r) {
            s00[r] = EXP2F(s00[r]); s01[r] = EXP2F(s01[r]);
            s10[r] = EXP2F(s10[r]); s11[r] = EXP2F(s11[r]);
        }

        // C-layout (row t=quad*4+r / 16+quad*4+r at col s) -> LDS P[s][t]
        int2 w0a = { pkrtz(s00[0], s00[1]), pkrtz(s00[2], s00[3]) };
        int2 w0b = { pkrtz(s01[0], s01[1]), pkrtz(s01[2], s01[3]) };
        *(int2*)(Prow0 + col * 40 + quad * 4)      = w0a;
        *(int2*)(Prow0 + col * 40 + 16 + quad * 4) = w0b;
        int2 w1a = { pkrtz(s10[0], s10[1]), pkrtz(s10[2], s10[3]) };
        int2 w1b = { pkrtz(s11[0], s11[1]), pkrtz(s11[2], s11[3]) };
        *(int2*)(Prow1 + col * 40 + quad * 4)      = w1a;
        *(int2*)(Prow1 + col * 40 + 16 + quad * 4) = w1b;

        // B-layout read: lane(quad,col) takes P[s=col][t=quad*8..quad*8+7]
        H8 p0, p1;
        p0.v = *(const int4*)(Prow0 + col * 40 + quad * 8);
        p1.v = *(const int4*)(Prow1 + col * 40 + quad * 8);

        acc0 = __builtin_amdgcn_mfma_f32_16x16x32_f16(vf.h, p0.h, acc0, 0, 0, 0);
        acc1 = __builtin_amdgcn_mfma_f32_16x16x32_f16(vf.h, p1.h, acc1, 0, 0, 0);
    }

    if (w > 0) { red[w - 1][0][lane] = acc0; red[w - 1][1][lane] = acc1; }
    __syncthreads();
    if (w == 0) {
        #pragma unroll
        for (int r = 0; r < 7; ++r) {
            acc0 += red[r][0][lane];
            acc1 += red[r][1][lane];
        }
        float inv0 = 1.0f / __shfl(acc0[0], 32 + col, 64);  // row 8 = denom
        float inv1 = 1.0f / __shfl(acc1[0], 32 + col, 64);
        if (quad < 2) {
            float* att = ws + WS_ATT + (size_t)(h * 8 + quad * 4) * S + q0;
            #pragma unroll
            for (int r = 0; r < 4; ++r) {
                att[r * S + col]      = acc0[r] * inv0;
                att[r * S + 16 + col] = acc1[r] * inv1;
            }
        }
    }
}

// ---------------- Out projection + bias + residual ----------------
// grid (16, 8), block 256: s-tile 256 (1 s/thread), o-tile 8
__global__ __launch_bounds__(256) void k_out(const float* __restrict__ x,
                                             const float* __restrict__ outw,
                                             const float* __restrict__ outb,
                                             const float* __restrict__ ws,
                                             float* __restrict__ out) {
    __shared__ float lw[512];
    __shared__ float lb[8];
    int tid = threadIdx.x;
    int o0 = blockIdx.y * 8;
    int s = blockIdx.x * 256 + tid;
    lw[tid]       = outw[o0 * 64 + tid];
    lw[tid + 256] = outw[o0 * 64 + 256 + tid];
    if (tid < 8) lb[tid] = outb[o0 + tid];
    __syncthreads();

    float acc[8];
    #pragma unroll
    for (int o = 0; o < 8; ++o) acc[o] = lb[o];
    const float* att = ws + WS_ATT;
    for (int c = 0; c < 64; ++c) {
        float av = att[c * S + s];
        #pragma unroll
        for (int o = 0; o < 8; ++o) acc[o] = fmaf(lw[o * 64 + c], av, acc[o]);
    }
    #pragma unroll
    for (int o = 0; o < 8; ++o)
        out[(o0 + o) * S + s] = acc[o] + x[(o0 + o) * S + s];
}

extern "C" void kernel_launch(void* const* d_in, const int* in_sizes, int n_in,
                              void* d_out, int out_size, void* d_ws, size_t ws_size,
                              hipStream_t stream) {
    const float* x    = (const float*)d_in[0];
    const float* gnw  = (const float*)d_in[1];
    const float* gnb  = (const float*)d_in[2];
    const float* qkvw = (const float*)d_in[3];
    const float* outw = (const float*)d_in[4];
    const float* outb = (const float*)d_in[5];
    float* out = (float*)d_out;
    float* ws  = (float*)d_ws;

    hipLaunchKernelGGL(k_gnstat1, dim3(64), dim3(256), 0, stream, x, ws);
    hipLaunchKernelGGL(k_qkv, dim3(16, 24), dim3(256), 0, stream, x, qkvw, gnw, gnb, ws);
    hipLaunchKernelGGL(k_attn, dim3(128, 8), dim3(512), 0, stream, ws);
    hipLaunchKernelGGL(k_out, dim3(16, 8), dim3(256), 0, stream, x, outw, outb, ws, out);
}

// Round 5
// 98.623 us; speedup vs baseline: 1.8541x; 1.0376x over previous
//
#include <hip/hip_runtime.h>
#include <math.h>

#define S 4096
#define EPS 1e-5f

#if __has_builtin(__builtin_amdgcn_exp2f)
#define EXP2F(x) __builtin_amdgcn_exp2f(x)
#else
#define EXP2F(x) exp2f(x)
#endif

// ws float-index offsets
#define WS_PSUM 0            // [64]
#define WS_PSQ  64           // [64]
#define WS_ATT  16384        // [64*4096] f32
// ws byte offsets for f16 regions (each 512 KB)
#define QT_B 1310720
#define KT_B 1835008
#define VB_B 2359296

typedef _Float16 h8_t __attribute__((ext_vector_type(8)));
typedef __fp16   fp16v2 __attribute__((ext_vector_type(2)));
typedef float    f4_t  __attribute__((ext_vector_type(4)));
typedef float    f16_t __attribute__((ext_vector_type(16)));

union H8 { h8_t h; int4 v; int i[4]; };

static __device__ __forceinline__ int pkrtz(float a, float b) {
    fp16v2 p = __builtin_amdgcn_cvt_pkrtz(a, b);
    union { fp16v2 h; int i; } u; u.h = p; return u.i;
}

// ---------------- GroupNorm stage 1: per-channel partial sums ----------------
__global__ __launch_bounds__(256) void k_gnstat1(const float* __restrict__ x,
                                                 float* __restrict__ ws) {
    int b = blockIdx.x;
    int tid = threadIdx.x;
    const float4* p = (const float4*)(x + b * 4096);
    float s = 0.f, sq = 0.f;
    #pragma unroll
    for (int i = 0; i < 4; ++i) {
        float4 v = p[tid + i * 256];
        s  += v.x + v.y + v.z + v.w;
        sq += v.x * v.x + v.y * v.y + v.z * v.z + v.w * v.w;
    }
    #pragma unroll
    for (int m = 32; m >= 1; m >>= 1) {
        s  += __shfl_xor(s, m);
        sq += __shfl_xor(sq, m);
    }
    __shared__ float ls[4], lq[4];
    int w = tid >> 6;
    if ((tid & 63) == 0) { ls[w] = s; lq[w] = sq; }
    __syncthreads();
    if (tid == 0) {
        ws[WS_PSUM + b] = ls[0] + ls[1] + ls[2] + ls[3];
        ws[WS_PSQ  + b] = lq[0] + lq[1] + lq[2] + lq[3];
    }
}

// ---------------- QKV projection (GN fold fused), writes f16 MFMA layouts ----------------
// grid (16, 24), block 256: s-tile 256 (1 s/thread), o-tile 8 (one head-slice)
__global__ __launch_bounds__(256) void k_qkv(const float* __restrict__ x,
                                             const float* __restrict__ qkvw,
                                             const float* __restrict__ gnw,
                                             const float* __restrict__ gnb,
                                             float* __restrict__ ws) {
    __shared__ float la[64], lb2[64], lw[512], lbias[8];
    int tid = threadIdx.x;
    int o0 = blockIdx.y * 8;
    int s = blockIdx.x * 256 + tid;

    if (tid < 64) {                 // finalize GN stats (redundant per block, cheap)
        float sm = ws[WS_PSUM + tid];
        float sq = ws[WS_PSQ + tid];
        #pragma unroll
        for (int m = 1; m < 8; m <<= 1) {
            sm += __shfl_xor(sm, m);
            sq += __shfl_xor(sq, m);
        }
        const float inv_n = 1.0f / 32768.0f;
        float mu  = sm * inv_n;
        float var = sq * inv_n - mu * mu;
        float rs  = rsqrtf(var + EPS);
        float a   = rs * gnw[tid];
        la[tid]  = a;
        lb2[tid] = gnb[tid] - mu * a;
    }
    __syncthreads();
    lw[tid]       = qkvw[o0 * 64 + tid]       * la[tid & 63];
    lw[tid + 256] = qkvw[o0 * 64 + 256 + tid] * la[tid & 63];
    {
        int wv = tid >> 6, ln = tid & 63;
        #pragma unroll
        for (int j = 0; j < 2; ++j) {
            int o = wv * 2 + j;
            float pb = qkvw[(o0 + o) * 64 + ln] * lb2[ln];
            #pragma unroll
            for (int m = 1; m < 64; m <<= 1) pb += __shfl_xor(pb, m);
            if (ln == 0) lbias[o] = pb;
        }
    }
    __syncthreads();

    float acc[8];
    #pragma unroll
    for (int o = 0; o < 8; ++o) acc[o] = lbias[o];
    for (int c = 0; c < 64; ++c) {
        float xv = x[c * S + s];
        #pragma unroll
        for (int o = 0; o < 8; ++o) acc[o] = fmaf(lw[o * 64 + c], xv, acc[o]);
    }

    char* base = (char*)ws;
    if (o0 < 64) {                       // Q -> Qt[h][s][d], pre-scaled by 8^-0.5*log2(e)
        const float qsc = 0.51006776f;
        int hh = o0 >> 3;
        int4 r;
        r.x = pkrtz(acc[0] * qsc, acc[1] * qsc);
        r.y = pkrtz(acc[2] * qsc, acc[3] * qsc);
        r.z = pkrtz(acc[4] * qsc, acc[5] * qsc);
        r.w = pkrtz(acc[6] * qsc, acc[7] * qsc);
        *(int4*)(base + QT_B + (size_t)(hh * 4096 + s) * 16) = r;
    } else if (o0 < 128) {               // K -> Kt[h][t][d]
        int hh = (o0 - 64) >> 3;
        int4 r;
        r.x = pkrtz(acc[0], acc[1]);
        r.y = pkrtz(acc[2], acc[3]);
        r.z = pkrtz(acc[4], acc[5]);
        r.w = pkrtz(acc[6], acc[7]);
        *(int4*)(base + KT_B + (size_t)(hh * 4096 + s) * 16) = r;
    } else {                             // V -> Vb[h][d][t]
        int hh = (o0 - 128) >> 3;
        _Float16* vb = (_Float16*)(base + VB_B);
        #pragma unroll
        for (int d = 0; d < 8; ++d)
            vb[(size_t)((hh * 8 + d) * 4096) + s] = (_Float16)acc[d];
    }
}

// ---------------- Attention via f16 MFMA ----------------
// grid (128, 8), block 512: 32 queries/block, 8 waves = 8 t-chunks of 512.
// QK: ONE 32x32x16 MFMA (A=K rows t, B=Q cols s; d=8 real, upper-half lanes
// zero). C-layout: col=lane&31 (s), t=(reg&3)+8*(reg>>2)+4*(lane>>5).
// exp2 in-place; per b=reg>>2 one ds_write_b64 of 4 contiguous t-halves to
// P[s][t] (stride 40 halves, bank-balanced). PV: 2x 16x16x32 with (V|ones)
// A-frag so acc row d=8 = softmax denominator. K/V register-prefetched.
__global__ __launch_bounds__(512, 8) void k_attn(float* __restrict__ ws) {
    const int h = blockIdx.y;
    const int q0 = blockIdx.x * 32;
    const int tid = threadIdx.x;
    const int w = tid >> 6;          // 0..7 t-chunk
    const int lane = tid & 63;
    const int col16 = lane & 15;
    const int quad = lane >> 4;
    const int col32 = lane & 31;
    const int half = lane >> 5;

    const char* base = (const char*)ws;
    const _Float16* Qt = (const _Float16*)(base + QT_B) + (size_t)h * 4096 * 8;
    const _Float16* Kt = (const _Float16*)(base + KT_B) + (size_t)h * 4096 * 8;
    const _Float16* Vb = (const _Float16*)(base + VB_B) + (size_t)h * 8 * 4096;

    __shared__ _Float16 Plds[8][32][40];   // per-wave 32s x 32t tile, +8 pad
    __shared__ f4_t red[7][2][64];

    // Q B-frag (32x32x16): lane<32 holds Q[s=col32][d=0..7]; upper half zero
    H8 qf;
    qf.i[0] = qf.i[1] = qf.i[2] = qf.i[3] = 0;
    if (half == 0) qf.v = *(const int4*)(Qt + (size_t)(q0 + col32) * 8);

    // K A-frag: lane<32 holds K[t=col32][d=0..7]; upper half stays zero
    H8 kf;
    kf.i[0] = kf.i[1] = kf.i[2] = kf.i[3] = 0;
    // V A-frag (16x16x32): row d=col16<8 data; d==8 ones (denominator); else 0
    H8 vf;
    {
        int c8 = (col16 == 8) ? 0x3C003C00 : 0;
        vf.i[0] = c8; vf.i[1] = c8; vf.i[2] = c8; vf.i[3] = c8;
    }

    const int tbase = w * 512;
    if (half == 0) kf.v = *(const int4*)(Kt + (size_t)(tbase + col32) * 8);
    if (col16 < 8) vf.v = *(const int4*)(Vb + (size_t)col16 * 4096 + tbase + quad * 8);

    f4_t acc0 = {0.f, 0.f, 0.f, 0.f};
    f4_t acc1 = {0.f, 0.f, 0.f, 0.f};
    f16_t zc = {0.f, 0.f, 0.f, 0.f, 0.f, 0.f, 0.f, 0.f,
                0.f, 0.f, 0.f, 0.f, 0.f, 0.f, 0.f, 0.f};
    _Float16* Pw = &Plds[w][0][0];

    for (int it = 0; it < 16; ++it) {
        H8 nk = kf, nv = vf;
        if (it < 15) {                       // prefetch next K/V tile
            const int tt = tbase + (it + 1) * 32;
            if (half == 0) nk.v = *(const int4*)(Kt + (size_t)(tt + col32) * 8);
            if (col16 < 8) nv.v = *(const int4*)(Vb + (size_t)col16 * 4096 + tt + quad * 8);
        }

        f16_t sc = __builtin_amdgcn_mfma_f32_32x32x16_f16(kf.h, qf.h, zc, 0, 0, 0);
        #pragma unroll
        for (int r = 0; r < 16; ++r) sc[r] = EXP2F(sc[r]);

        // b=reg>>2: t = 8b + 4*half + {0..3}, s=col32 -> one b64 per b
        #pragma unroll
        for (int b = 0; b < 4; ++b) {
            int2 wv = { pkrtz(sc[4 * b], sc[4 * b + 1]),
                        pkrtz(sc[4 * b + 2], sc[4 * b + 3]) };
            *(int2*)(Pw + col32 * 40 + 8 * b + 4 * half) = wv;
        }

        // B-frag reads: lane(quad,col16) takes P[s][t=quad*8..+7]
        H8 p0, p1;
        p0.v = *(const int4*)(Pw + col16 * 40 + quad * 8);
        p1.v = *(const int4*)(Pw + (col16 + 16) * 40 + quad * 8);

        acc0 = __builtin_amdgcn_mfma_f32_16x16x32_f16(vf.h, p0.h, acc0, 0, 0, 0);
        acc1 = __builtin_amdgcn_mfma_f32_16x16x32_f16(vf.h, p1.h, acc1, 0, 0, 0);

        kf = nk; vf = nv;
    }

    if (w > 0) { red[w - 1][0][lane] = acc0; red[w - 1][1][lane] = acc1; }
    __syncthreads();
    if (w == 0) {
        #pragma unroll
        for (int r = 0; r < 7; ++r) {
            acc0 += red[r][0][lane];
            acc1 += red[r][1][lane];
        }
        float inv0 = 1.0f / __shfl(acc0[0], 32 + col16, 64);  // row d=8 = denom
        float inv1 = 1.0f / __shfl(acc1[0], 32 + col16, 64);
        if (quad < 2) {
            float* att = ws + WS_ATT + (size_t)(h * 8 + quad * 4) * S + q0;
            #pragma unroll
            for (int r = 0; r < 4; ++r) {
                att[r * S + col16]      = acc0[r] * inv0;
                att[r * S + 16 + col16] = acc1[r] * inv1;
            }
        }
    }
}

// ---------------- Out projection + bias + residual ----------------
// grid (16, 8), block 256: s-tile 256 (1 s/thread), o-tile 8
__global__ __launch_bounds__(256) void k_out(const float* __restrict__ x,
                                             const float* __restrict__ outw,
                                             const float* __restrict__ outb,
                                             const float* __restrict__ ws,
                                             float* __restrict__ out) {
    __shared__ float lw[512];
    __shared__ float lb[8];
    int tid = threadIdx.x;
    int o0 = blockIdx.y * 8;
    int s = blockIdx.x * 256 + tid;
    lw[tid]       = outw[o0 * 64 + tid];
    lw[tid + 256] = outw[o0 * 64 + 256 + tid];
    if (tid < 8) lb[tid] = outb[o0 + tid];
    __syncthreads();

    float acc[8];
    #pragma unroll
    for (int o = 0; o < 8; ++o) acc[o] = lb[o];
    const float* att = ws + WS_ATT;
    for (int c = 0; c < 64; ++c) {
        float av = att[c * S + s];
        #pragma unroll
        for (int o = 0; o < 8; ++o) acc[o] = fmaf(lw[o * 64 + c], av, acc[o]);
    }
    #pragma unroll
    for (int o = 0; o < 8; ++o)
        out[(o0 + o) * S + s] = acc[o] + x[(o0 + o) * S + s];
}

extern "C" void kernel_launch(void* const* d_in, const int* in_sizes, int n_in,
                              void* d_out, int out_size, void* d_ws, size_t ws_size,
                              hipStream_t stream) {
    const float* x    = (const float*)d_in[0];
    const float* gnw  = (const float*)d_in[1];
    const float* gnb  = (const float*)d_in[2];
    const float* qkvw = (const float*)d_in[3];
    const float* outw = (const float*)d_in[4];
    const float* outb = (const float*)d_in[5];
    float* out = (float*)d_out;
    float* ws  = (float*)d_ws;

    hipLaunchKernelGGL(k_gnstat1, dim3(64), dim3(256), 0, stream, x, ws);
    hipLaunchKernelGGL(k_qkv, dim3(16, 24), dim3(256), 0, stream, x, qkvw, gnw, gnb, ws);
    hipLaunchKernelGGL(k_attn, dim3(128, 8), dim3(512), 0, stream, ws);
    hipLaunchKernelGGL(k_out, dim3(16, 8), dim3(256), 0, stream, x, outw, outb, ws, out);
}